// Round 5
// baseline (112.043 us; speedup 1.0000x reference)
//
#include <hip/hip_runtime.h>

// Exact KNN (faiss-equivalent, (dist,idx)-lexicographic ties) + fused neighbor
// feature sum. N=65536 pts on 128^3 int grid, K=16, C=64.
//
// Cells = 4^3 coords -> 32^3 = 32768 cells, ~2 pts/cell. Key = (d2<<16)|idx
// (d2 <= 48387 < 2^16): unsigned order == (dist, idx) lexicographic.
//
// PROLOGUE (r1-r3 lesson): grid barriers cost ~8us each on MI355X regardless
// of poll discipline -> no barriers, 5 slim dispatches, driver ordering.
// r4 lesson: chunk-permuted layout doubled knn FETCH (13->27MB). Fix: global
// CELL ORDER restored deterministically without a global scan: cell_count
// also accumulates 128 per-chunk totals; each scan_chunk block computes its
// chunk base as a reduce-sum of chunktot[0..chunk) (15 ops, wave-redundant),
// then local-scans its 256 cells. starts[c+1] is again a valid row-end
// sentinel everywhere (contiguous global layout) -> ends[] dropped.
//
// knn_search (r5): wave = 16 queries x 4 slices (was 8x8). Merge-tree depth
// drops 3->2 levels; per-query sort VALU = (32 inserts*21 + 2 merges*112)
// *64/16 = 3584 vs 5376 (-33%). Lane owns 4 whole rows (y = ya+slice,
// z = za+0..3); 4 streams x 2-unroll = 8 predicated loads in flight.
// Main scan = quadrant-aligned 4x4x4 cell box, SHIFT-clamped to the grid
// (origin clamp [0,28]) so the box is always full 4x4x4. Guarantee:
// uncovered min-d2 >= 49. Per-lane sorted top-16 via med3 insert network
// (insert order irrelevant: top-k set). FINAL merge keeps only the min-half
// (bitonic, unsorted) since the gather is a set-sum; redo bound via
// max-tree; cold redo path (P~1e-7/query) re-sorts first, then full redo:
// r<=2 cube, then Chebyshev shells r>=3 (shell-r min-d2 = (4r-3)^2).
// Gather fused: lane = 4 channels x 16 lanes/query, 4 passes x 4 queries;
// float4 feature-row loads; output written directly.

typedef unsigned int uint;
typedef unsigned short ushort;
typedef short short2v __attribute__((ext_vector_type(2)));

#define NPTS   65536
#define NCELL  32768

static __device__ inline short2v u2s(uint v) { union { uint u; short2v s; } c; c.u = v; return c.s; }
static __device__ inline uint s2u(short2v v) { union { uint u; short2v s; } c; c.s = v; return c.u; }

static __device__ inline int dot2acc(short2v a, short2v b, int c) {
#if __has_builtin(__builtin_amdgcn_sdot2)
    return __builtin_amdgcn_sdot2(a, b, c, false);
#else
    return (int)a.x * (int)b.x + (int)a.y * (int)b.y + c;
#endif
}

__global__ __launch_bounds__(256) void cell_count(const int* __restrict__ coords,
                                                  uint* __restrict__ counts,
                                                  uint* __restrict__ chunktot) {
    int i = blockIdx.x * 256 + threadIdx.x;
    int x = coords[3 * i + 0], y = coords[3 * i + 1], z = coords[3 * i + 2];
    int cell = (x >> 2) | ((y >> 2) << 5) | ((z >> 2) << 10);
    atomicAdd(&counts[cell], 1u);
    atomicAdd(&chunktot[cell >> 8], 1u);   // 128 chunk totals for barrier-free global order
}

// Deterministic cell-ordered scan, no grid barrier: chunk base = sum of
// chunktot[0..chunk) computed wave-redundantly, + block-local scan of 256.
__global__ __launch_bounds__(256) void scan_chunk(const uint* __restrict__ counts,
                                                  const uint* __restrict__ chunktot,
                                                  uint* __restrict__ starts,
                                                  uint* __restrict__ cursors) {
    __shared__ uint wsum[4];
    int b = blockIdx.x;                  // chunk id, 0..127
    int tid = threadIdx.x;
    int lane = tid & 63, wv = tid >> 6;
    int cell = b * 256 + tid;

    // chunk base: sum of chunktot[j] for j < b (each wave computes it)
    uint t0 = chunktot[lane];
    uint t1 = chunktot[64 + lane];
    uint s = (lane < b ? t0 : 0u) + (64 + lane < b ? t1 : 0u);
#pragma unroll
    for (int off = 32; off; off >>= 1) s += __shfl_xor(s, off, 64);
    uint base = s;

    uint c = counts[cell];
    uint v = c;
#pragma unroll
    for (int off = 1; off < 64; off <<= 1) {
        uint u = __shfl_up(v, off, 64);
        if (lane >= off) v += u;
    }
    if (lane == 63) wsum[wv] = v;
    __syncthreads();
    uint woff = 0;
#pragma unroll
    for (int j = 0; j < 4; ++j) woff += (j < wv) ? wsum[j] : 0u;
    uint st = base + woff + v - c;
    starts[cell]  = st;
    cursors[cell] = st;
    if (cell == NCELL - 1) starts[NCELL] = st + c;   // = 65536
}

__global__ __launch_bounds__(256) void cell_scatter(const int* __restrict__ coords,
                                                    uint* __restrict__ cursors,
                                                    uint2* __restrict__ sorted) {
    int i = blockIdx.x * 256 + threadIdx.x;
    int x = coords[3 * i + 0], y = coords[3 * i + 1], z = coords[3 * i + 2];
    int cell = (x >> 2) | ((y >> 2) << 5) | ((z >> 2) << 10);
    uint pos = atomicAdd(&cursors[cell], 1u);
    // packed for v_pk_sub_i16 / v_dot2: w0 = x | y<<16, w1 = idx | z<<16
    sorted[pos] = make_uint2((uint)(x | (y << 16)), (uint)(i | (z << 16)));
}

__global__ __launch_bounds__(256, 4) void knn_search(const uint* __restrict__ starts,
                                                     const uint2* __restrict__ sorted,
                                                     const float* __restrict__ feat,
                                                     float* __restrict__ out) {
    // XCD-chunked swizzle: consecutive logical blocks -> same XCD L2.
    int blk  = (blockIdx.x & 7) * 128 + (blockIdx.x >> 3);   // 1024 blocks
    int wave = threadIdx.x >> 6;                             // 4 waves/block
    int lane = threadIdx.x & 63;
    int qslot = lane & 15;                                   // 16 queries/wave
    int slice = lane >> 4;                                   // 4 slices/query
    int qpos = blk * 64 + wave * 16 + qslot;

    uint2 me = sorted[qpos];
    uint qxy = me.x;                       // qx | qy<<16
    uint qzp = me.y & 0xFFFF0000u;         // qz<<16
    uint qidx = me.y & 0xFFFFu;            // original index
    int qx = (int)(me.x & 0xFFFFu);
    int qy = (int)(me.x >> 16);
    int qz = (int)(me.y >> 16);
    int cx = qx >> 2, cy = qy >> 2, cz = qz >> 2;

    uint k[16];
#pragma unroll
    for (int j = 0; j < 16; ++j) k[j] = 0xFFFFFFFFu;

    auto insert1 = [&](uint2 pt) {
        short2v A = u2s(pt.x) - u2s(qxy);          // (dx, dy)
        short2v B = u2s(pt.y) - u2s(qzp);          // (idx, dz)
        uint Bu = s2u(B);
        short2v Bm = u2s(Bu & 0xFFFF0000u);        // (0, dz)
        int d2 = dot2acc(A, A, dot2acc(Bm, Bm, 0));
        uint key = ((uint)d2 << 16) + (Bu & 0xFFFFu);
        // in-place descending med3 chain: 15 independent ops (reads old j-1)
#pragma unroll
        for (int j = 15; j >= 1; --j)
            asm("v_med3_u32 %0, %1, %2, %3"
                : "=v"(k[j]) : "v"(k[j - 1]), "v"(k[j]), "v"(key));
        k[0] = min(k[0], key);
    };

    // sliced scan (stride 4 across slices) -- used only by the cold redo path
    auto scan4 = [&](uint p0, uint p1) {
        for (uint p = p0 + (uint)slice; p < p1; p += 4u) insert1(sorted[p]);
    };

    // bitonic min-half with partner lane (lane ^ mask): k becomes a bitonic
    // sequence holding the exact top-16 SET of the pair
    auto merge_min = [&](int mask) {
        uint b[16];
#pragma unroll
        for (int j = 0; j < 16; ++j) b[j] = __shfl_xor(k[j], mask, 64);
#pragma unroll
        for (int j = 0; j < 16; ++j) k[j] = min(k[j], b[15 - j]);
    };
    // bitonic cleanup: sorts the bitonic sequence ascending
    auto clean = [&]() {
#pragma unroll
        for (int d = 8; d >= 1; d >>= 1) {
#pragma unroll
            for (int i = 0; i < 16; ++i) {
                if ((i & d) == 0) {
                    uint lo = min(k[i], k[i + d]);
                    uint hi = max(k[i], k[i + d]);
                    k[i] = lo;
                    k[i + d] = hi;
                }
            }
        }
    };
    auto merge = [&](int mask) { merge_min(mask); clean(); };
    auto merge_all = [&]() { merge(16); merge(32); };

    // ---- quadrant-aligned 4x4x4 box, SHIFT-clamped (always full size) ----
    int xa = min(max(cx - ((qx & 3) < 2 ? 2 : 1), 0), 28);
    int ya = min(max(cy - ((qy & 3) < 2 ? 2 : 1), 0), 28);
    int za = min(max(cz - ((qz & 3) < 2 ? 2 : 1), 0), 28);

    // lane owns 4 whole rows: y = ya+slice, z = za+0..3. 4 streams,
    // 2x-unrolled: 8 predicated loads in flight per iteration.
    {
        int ybase = (ya + slice) << 5;
        int rb0 = ybase | ((za + 0) << 10);
        int rb1 = ybase | ((za + 1) << 10);
        int rb2 = ybase | ((za + 2) << 10);
        int rb3 = ybase | ((za + 3) << 10);
        uint pA = starts[rb0 + xa], eA = starts[rb0 + xa + 4];
        uint pB = starts[rb1 + xa], eB = starts[rb1 + xa + 4];
        uint pC = starts[rb2 + xa], eC = starts[rb2 + xa + 4];
        uint pD = starts[rb3 + xa], eD = starts[rb3 + xa + 4];
        while (__any((pA < eA) || (pB < eB) || (pC < eC) || (pD < eD))) {
            bool a0 = pA < eA, a1 = pA + 1 < eA;
            bool b0 = pB < eB, b1 = pB + 1 < eB;
            bool c0 = pC < eC, c1 = pC + 1 < eC;
            bool d0 = pD < eD, d1 = pD + 1 < eD;
            uint2 A0, A1, B0, B1, C0, C1, D0, D1;
            if (a0) A0 = sorted[pA];
            if (a1) A1 = sorted[pA + 1];
            if (b0) B0 = sorted[pB];
            if (b1) B1 = sorted[pB + 1];
            if (c0) C0 = sorted[pC];
            if (c1) C1 = sorted[pC + 1];
            if (d0) D0 = sorted[pD];
            if (d1) D1 = sorted[pD + 1];
            pA += (a0 ? 1u : 0u) + (a1 ? 1u : 0u);
            pB += (b0 ? 1u : 0u) + (b1 ? 1u : 0u);
            pC += (c0 ? 1u : 0u) + (c1 ? 1u : 0u);
            pD += (d0 ? 1u : 0u) + (d1 ? 1u : 0u);
            if (a0) insert1(A0);
            if (b0) insert1(B0);
            if (c0) insert1(C0);
            if (d0) insert1(D0);
            if (a1) insert1(A1);
            if (b1) insert1(B1);
            if (c1) insert1(C1);
            if (d1) insert1(D1);
        }
    }
    // exact top-16 SET over the box (final merge leaves k bitonic-unsorted;
    // the gather is a set-sum so order is irrelevant on the hot path)
    merge(16); merge_min(32);
    uint mx = k[0];
#pragma unroll
    for (int j = 1; j < 16; ++j) mx = max(mx, k[j]);

    // ---- cold redo: uncovered space has min-d2 >= 49 (P ~ 1e-7/query) ----
    bool redo = (mx >> 16) >= 49u;
    if (__any(redo)) {
        clean();   // restore sorted order: merge machinery needs sorted inputs
        // triggered queries: discard everything, rescan from scratch (sliced).
        // others: keep slice 0 only (slices!=0 must reset before re-merge).
        if (redo || slice != 0) {
#pragma unroll
            for (int j = 0; j < 16; ++j) k[j] = 0xFFFFFFFFu;
        }
        if (redo) {
            int xl = max(cx - 2, 0), xh = min(cx + 2, 31);
            int yl = max(cy - 2, 0), yh = min(cy + 2, 31);
            int zl = max(cz - 2, 0), zh = min(cz + 2, 31);
            for (int z = zl; z <= zh; ++z)
                for (int y = yl; y <= yh; ++y) {
                    int rb = (y << 5) | (z << 10);
                    scan4(starts[rb + xl], starts[rb + xh + 1]);
                }
        }
        merge_all();
        for (int r = 3; r < 32; ++r) {
            uint b = (uint)(4 * r - 3);
            bool active = (k[15] >> 16) >= b * b;
            if (!__any(active)) break;
            if (slice != 0) {
#pragma unroll
                for (int j = 0; j < 16; ++j) k[j] = 0xFFFFFFFFu;
            }
            if (active) {
                int z0 = cz - r < 0 ? 0 : cz - r;
                int z1 = cz + r > 31 ? 31 : cz + r;
                for (int z = z0; z <= z1; ++z) {
                    bool zface = (z == cz - r) || (z == cz + r);
                    int y0 = cy - r < 0 ? 0 : cy - r;
                    int y1 = cy + r > 31 ? 31 : cy + r;
                    for (int y = y0; y <= y1; ++y) {
                        bool face = zface || (y == cy - r) || (y == cy + r);
                        int rb = (y << 5) | (z << 10);
                        if (face) {
                            int x0 = cx - r < 0 ? 0 : cx - r;
                            int x1 = cx + r > 31 ? 31 : cx + r;
                            scan4(starts[rb + x0], starts[rb + x1 + 1]);
                        } else {
                            int xL = cx - r;
                            if (xL >= 0) scan4(starts[rb + xL], starts[rb + xL + 1]);
                            int xR = cx + r;
                            if (xR <= 31) scan4(starts[rb + xR], starts[rb + xR + 1]);
                        }
                    }
                }
            }
            merge_all();
        }
    }

    // ---- fused gather: float4 channels, 4 passes x 4 queries ----
    uint ki[16];
#pragma unroll
    for (int j = 0; j < 16; ++j) ki[j] = k[j] & 0xFFFFu;

    int ch = lane & 15;          // float4 channel group (4 channels)
    int qg = lane >> 4;          // query within pass
#pragma unroll
    for (int p = 0; p < 4; ++p) {
        int qs = p * 4 + qg;     // query slot 0..15; lane qs holds it (slice 0)
        uint qorig = __shfl(qidx, qs, 64);
        float4 acc = make_float4(0.f, 0.f, 0.f, 0.f);
#pragma unroll
        for (int j = 0; j < 16; ++j) {
            uint nj = __shfl(ki[j], qs, 64);
            float4 v = reinterpret_cast<const float4*>(feat)[nj * 16u + (uint)ch];
            acc.x += v.x; acc.y += v.y; acc.z += v.z; acc.w += v.w;
        }
        reinterpret_cast<float4*>(out)[qorig * 16u + (uint)ch] = acc;
    }
}

extern "C" void kernel_launch(void* const* d_in, const int* in_sizes, int n_in,
                              void* d_out, int out_size, void* d_ws, size_t ws_size,
                              hipStream_t stream) {
    const int*   coords = (const int*)d_in[0];
    const float* feat   = (const float*)d_in[1];
    float*       out    = (float*)d_out;

    uint* W = (uint*)d_ws;
    uint*  chunktot = W;                      // 128, memset-zeroed
    uint*  counts   = W + 128;                // 32768, memset-zeroed
    uint*  starts   = W + 32896;              // 32769
    uint*  cursors  = W + 65668;              // 32768 (16B aligned)
    uint2* sorted   = (uint2*)(W + 98436);    // 65536 * 8 B (16B aligned)

    hipMemsetAsync(W, 0, (128 + NCELL) * sizeof(uint), stream);
    cell_count<<<NPTS / 256, 256, 0, stream>>>(coords, counts, chunktot);
    scan_chunk<<<NCELL / 256, 256, 0, stream>>>(counts, chunktot, starts, cursors);
    cell_scatter<<<NPTS / 256, 256, 0, stream>>>(coords, cursors, sorted);
    knn_search<<<1024, 256, 0, stream>>>(starts, sorted, feat, out);
}

// Round 6
// 61.535 us; speedup vs baseline: 1.8208x; 1.8208x over previous
//
#include <hip/hip_runtime.h>

// Exact KNN (faiss-equivalent, (dist,idx)-lexicographic ties) + fused neighbor
// feature sum. N=65536 pts on 128^3 int grid, K=16, C=64.
//
// Cells = 4^3 coords -> 32^3 = 32768 cells, ~2 pts/cell. Key = (d2<<16)|idx
// (d2 <= 48387 < 2^16): unsigned order == (dist, idx) lexicographic.
//
// PROLOGUE lessons:
//  r1-r3: grid barriers cost ~8us each on MI355X regardless of poll
//         discipline -> no barriers; slim dispatches; driver ordering.
//  r4:    arrival-ordered chunk bases permute 'sorted' -> knn FETCH 2x.
//  r5:    atomicAdd into 128 chunk counters = ~512 same-address RMWs per
//         line ~ 100ns each -> 56us. RULE: same-address RMW ~100ns; keep
//         per-address atomic multiplicity < ~100.
//  r6:    chunk totals via a dedicated contention-free reduce dispatch
//         (coalesced loads + one plain store per block). Deterministic
//         cell-ordered layout, no atomics beyond the per-cell histogram.
//
// knn_search: wave = 16 queries x 4 slices. Merge-tree depth 2 (vs 3 at
// 8x8); per-query sort VALU = (32 inserts*21 + 2 merges*112)*64/16 = 3584
// vs 5376 (-33%). Lane owns 4 whole rows (y = ya+slice, z = za+0..3);
// 4 streams x 2-unroll = 8 predicated loads in flight. Main scan =
// quadrant-aligned 4x4x4 cell box, SHIFT-clamped to the grid (origin clamp
// [0,28]) so the box is always full 4x4x4. Guarantee: uncovered min-d2 >=
// 49. Per-lane sorted top-16 via med3 insert network (insert order
// irrelevant: top-k set). FINAL merge keeps only the min-half (bitonic,
// unsorted) since the gather is a set-sum; redo bound via max-tree; cold
// redo path (P~1e-7/query) re-sorts first, then full redo: r<=2 cube, then
// Chebyshev shells r>=3 (shell-r min-d2 = (4r-3)^2).
// Gather fused: lane = 4 channels x 16 lanes/query, 4 passes x 4 queries;
// float4 feature-row loads; output written directly.

typedef unsigned int uint;
typedef unsigned short ushort;
typedef short short2v __attribute__((ext_vector_type(2)));

#define NPTS   65536
#define NCELL  32768

static __device__ inline short2v u2s(uint v) { union { uint u; short2v s; } c; c.u = v; return c.s; }
static __device__ inline uint s2u(short2v v) { union { uint u; short2v s; } c; c.s = v; return c.u; }

static __device__ inline int dot2acc(short2v a, short2v b, int c) {
#if __has_builtin(__builtin_amdgcn_sdot2)
    return __builtin_amdgcn_sdot2(a, b, c, false);
#else
    return (int)a.x * (int)b.x + (int)a.y * (int)b.y + c;
#endif
}

__global__ __launch_bounds__(256) void cell_count(const int* __restrict__ coords,
                                                  uint* __restrict__ counts) {
    int i = blockIdx.x * 256 + threadIdx.x;
    int x = coords[3 * i + 0], y = coords[3 * i + 1], z = coords[3 * i + 2];
    int cell = (x >> 2) | ((y >> 2) << 5) | ((z >> 2) << 10);
    atomicAdd(&counts[cell], 1u);
}

// Contention-free chunk totals: block j reduces counts[j*256 .. j*256+255]
// (coalesced) and plain-stores one value. No atomics.
__global__ __launch_bounds__(256) void chunk_reduce(const uint* __restrict__ counts,
                                                    uint* __restrict__ chunktot) {
    __shared__ uint wsum[4];
    int tid = threadIdx.x;
    int lane = tid & 63, wv = tid >> 6;
    uint c = counts[blockIdx.x * 256 + tid];
#pragma unroll
    for (int off = 32; off; off >>= 1) c += __shfl_xor(c, off, 64);
    if (lane == 0) wsum[wv] = c;
    __syncthreads();
    if (tid == 0) chunktot[blockIdx.x] = wsum[0] + wsum[1] + wsum[2] + wsum[3];
}

// Deterministic cell-ordered scan, no grid barrier: chunk base = sum of
// chunktot[0..chunk) computed wave-redundantly, + block-local scan of 256.
__global__ __launch_bounds__(256) void scan_chunk(const uint* __restrict__ counts,
                                                  const uint* __restrict__ chunktot,
                                                  uint* __restrict__ starts,
                                                  uint* __restrict__ cursors) {
    __shared__ uint wsum[4];
    int b = blockIdx.x;                  // chunk id, 0..127
    int tid = threadIdx.x;
    int lane = tid & 63, wv = tid >> 6;
    int cell = b * 256 + tid;

    // chunk base: sum of chunktot[j] for j < b (each wave computes it)
    uint t0 = chunktot[lane];
    uint t1 = chunktot[64 + lane];
    uint s = (lane < b ? t0 : 0u) + (64 + lane < b ? t1 : 0u);
#pragma unroll
    for (int off = 32; off; off >>= 1) s += __shfl_xor(s, off, 64);
    uint base = s;

    uint c = counts[cell];
    uint v = c;
#pragma unroll
    for (int off = 1; off < 64; off <<= 1) {
        uint u = __shfl_up(v, off, 64);
        if (lane >= off) v += u;
    }
    if (lane == 63) wsum[wv] = v;
    __syncthreads();
    uint woff = 0;
#pragma unroll
    for (int j = 0; j < 4; ++j) woff += (j < wv) ? wsum[j] : 0u;
    uint st = base + woff + v - c;
    starts[cell]  = st;
    cursors[cell] = st;
    if (cell == NCELL - 1) starts[NCELL] = st + c;   // = 65536
}

__global__ __launch_bounds__(256) void cell_scatter(const int* __restrict__ coords,
                                                    uint* __restrict__ cursors,
                                                    uint2* __restrict__ sorted) {
    int i = blockIdx.x * 256 + threadIdx.x;
    int x = coords[3 * i + 0], y = coords[3 * i + 1], z = coords[3 * i + 2];
    int cell = (x >> 2) | ((y >> 2) << 5) | ((z >> 2) << 10);
    uint pos = atomicAdd(&cursors[cell], 1u);
    // packed for v_pk_sub_i16 / v_dot2: w0 = x | y<<16, w1 = idx | z<<16
    sorted[pos] = make_uint2((uint)(x | (y << 16)), (uint)(i | (z << 16)));
}

__global__ __launch_bounds__(256, 4) void knn_search(const uint* __restrict__ starts,
                                                     const uint2* __restrict__ sorted,
                                                     const float* __restrict__ feat,
                                                     float* __restrict__ out) {
    // XCD-chunked swizzle: consecutive logical blocks -> same XCD L2.
    int blk  = (blockIdx.x & 7) * 128 + (blockIdx.x >> 3);   // 1024 blocks
    int wave = threadIdx.x >> 6;                             // 4 waves/block
    int lane = threadIdx.x & 63;
    int qslot = lane & 15;                                   // 16 queries/wave
    int slice = lane >> 4;                                   // 4 slices/query
    int qpos = blk * 64 + wave * 16 + qslot;

    uint2 me = sorted[qpos];
    uint qxy = me.x;                       // qx | qy<<16
    uint qzp = me.y & 0xFFFF0000u;         // qz<<16
    uint qidx = me.y & 0xFFFFu;            // original index
    int qx = (int)(me.x & 0xFFFFu);
    int qy = (int)(me.x >> 16);
    int qz = (int)(me.y >> 16);
    int cx = qx >> 2, cy = qy >> 2, cz = qz >> 2;

    uint k[16];
#pragma unroll
    for (int j = 0; j < 16; ++j) k[j] = 0xFFFFFFFFu;

    auto insert1 = [&](uint2 pt) {
        short2v A = u2s(pt.x) - u2s(qxy);          // (dx, dy)
        short2v B = u2s(pt.y) - u2s(qzp);          // (idx, dz)
        uint Bu = s2u(B);
        short2v Bm = u2s(Bu & 0xFFFF0000u);        // (0, dz)
        int d2 = dot2acc(A, A, dot2acc(Bm, Bm, 0));
        uint key = ((uint)d2 << 16) + (Bu & 0xFFFFu);
        // in-place descending med3 chain: 15 independent ops (reads old j-1)
#pragma unroll
        for (int j = 15; j >= 1; --j)
            asm("v_med3_u32 %0, %1, %2, %3"
                : "=v"(k[j]) : "v"(k[j - 1]), "v"(k[j]), "v"(key));
        k[0] = min(k[0], key);
    };

    // sliced scan (stride 4 across slices) -- used only by the cold redo path
    auto scan4 = [&](uint p0, uint p1) {
        for (uint p = p0 + (uint)slice; p < p1; p += 4u) insert1(sorted[p]);
    };

    // bitonic min-half with partner lane (lane ^ mask): k becomes a bitonic
    // sequence holding the exact top-16 SET of the pair
    auto merge_min = [&](int mask) {
        uint b[16];
#pragma unroll
        for (int j = 0; j < 16; ++j) b[j] = __shfl_xor(k[j], mask, 64);
#pragma unroll
        for (int j = 0; j < 16; ++j) k[j] = min(k[j], b[15 - j]);
    };
    // bitonic cleanup: sorts the bitonic sequence ascending
    auto clean = [&]() {
#pragma unroll
        for (int d = 8; d >= 1; d >>= 1) {
#pragma unroll
            for (int i = 0; i < 16; ++i) {
                if ((i & d) == 0) {
                    uint lo = min(k[i], k[i + d]);
                    uint hi = max(k[i], k[i + d]);
                    k[i] = lo;
                    k[i + d] = hi;
                }
            }
        }
    };
    auto merge = [&](int mask) { merge_min(mask); clean(); };
    auto merge_all = [&]() { merge(16); merge(32); };

    // ---- quadrant-aligned 4x4x4 box, SHIFT-clamped (always full size) ----
    int xa = min(max(cx - ((qx & 3) < 2 ? 2 : 1), 0), 28);
    int ya = min(max(cy - ((qy & 3) < 2 ? 2 : 1), 0), 28);
    int za = min(max(cz - ((qz & 3) < 2 ? 2 : 1), 0), 28);

    // lane owns 4 whole rows: y = ya+slice, z = za+0..3. 4 streams,
    // 2x-unrolled: 8 predicated loads in flight per iteration.
    {
        int ybase = (ya + slice) << 5;
        int rb0 = ybase | ((za + 0) << 10);
        int rb1 = ybase | ((za + 1) << 10);
        int rb2 = ybase | ((za + 2) << 10);
        int rb3 = ybase | ((za + 3) << 10);
        uint pA = starts[rb0 + xa], eA = starts[rb0 + xa + 4];
        uint pB = starts[rb1 + xa], eB = starts[rb1 + xa + 4];
        uint pC = starts[rb2 + xa], eC = starts[rb2 + xa + 4];
        uint pD = starts[rb3 + xa], eD = starts[rb3 + xa + 4];
        while (__any((pA < eA) || (pB < eB) || (pC < eC) || (pD < eD))) {
            bool a0 = pA < eA, a1 = pA + 1 < eA;
            bool b0 = pB < eB, b1 = pB + 1 < eB;
            bool c0 = pC < eC, c1 = pC + 1 < eC;
            bool d0 = pD < eD, d1 = pD + 1 < eD;
            uint2 A0, A1, B0, B1, C0, C1, D0, D1;
            if (a0) A0 = sorted[pA];
            if (a1) A1 = sorted[pA + 1];
            if (b0) B0 = sorted[pB];
            if (b1) B1 = sorted[pB + 1];
            if (c0) C0 = sorted[pC];
            if (c1) C1 = sorted[pC + 1];
            if (d0) D0 = sorted[pD];
            if (d1) D1 = sorted[pD + 1];
            pA += (a0 ? 1u : 0u) + (a1 ? 1u : 0u);
            pB += (b0 ? 1u : 0u) + (b1 ? 1u : 0u);
            pC += (c0 ? 1u : 0u) + (c1 ? 1u : 0u);
            pD += (d0 ? 1u : 0u) + (d1 ? 1u : 0u);
            if (a0) insert1(A0);
            if (b0) insert1(B0);
            if (c0) insert1(C0);
            if (d0) insert1(D0);
            if (a1) insert1(A1);
            if (b1) insert1(B1);
            if (c1) insert1(C1);
            if (d1) insert1(D1);
        }
    }
    // exact top-16 SET over the box (final merge leaves k bitonic-unsorted;
    // the gather is a set-sum so order is irrelevant on the hot path)
    merge(16); merge_min(32);
    uint mx = k[0];
#pragma unroll
    for (int j = 1; j < 16; ++j) mx = max(mx, k[j]);

    // ---- cold redo: uncovered space has min-d2 >= 49 (P ~ 1e-7/query) ----
    bool redo = (mx >> 16) >= 49u;
    if (__any(redo)) {
        clean();   // restore sorted order: merge machinery needs sorted inputs
        // triggered queries: discard everything, rescan from scratch (sliced).
        // others: keep slice 0 only (slices!=0 must reset before re-merge).
        if (redo || slice != 0) {
#pragma unroll
            for (int j = 0; j < 16; ++j) k[j] = 0xFFFFFFFFu;
        }
        if (redo) {
            int xl = max(cx - 2, 0), xh = min(cx + 2, 31);
            int yl = max(cy - 2, 0), yh = min(cy + 2, 31);
            int zl = max(cz - 2, 0), zh = min(cz + 2, 31);
            for (int z = zl; z <= zh; ++z)
                for (int y = yl; y <= yh; ++y) {
                    int rb = (y << 5) | (z << 10);
                    scan4(starts[rb + xl], starts[rb + xh + 1]);
                }
        }
        merge_all();
        for (int r = 3; r < 32; ++r) {
            uint b = (uint)(4 * r - 3);
            bool active = (k[15] >> 16) >= b * b;
            if (!__any(active)) break;
            if (slice != 0) {
#pragma unroll
                for (int j = 0; j < 16; ++j) k[j] = 0xFFFFFFFFu;
            }
            if (active) {
                int z0 = cz - r < 0 ? 0 : cz - r;
                int z1 = cz + r > 31 ? 31 : cz + r;
                for (int z = z0; z <= z1; ++z) {
                    bool zface = (z == cz - r) || (z == cz + r);
                    int y0 = cy - r < 0 ? 0 : cy - r;
                    int y1 = cy + r > 31 ? 31 : cy + r;
                    for (int y = y0; y <= y1; ++y) {
                        bool face = zface || (y == cy - r) || (y == cy + r);
                        int rb = (y << 5) | (z << 10);
                        if (face) {
                            int x0 = cx - r < 0 ? 0 : cx - r;
                            int x1 = cx + r > 31 ? 31 : cx + r;
                            scan4(starts[rb + x0], starts[rb + x1 + 1]);
                        } else {
                            int xL = cx - r;
                            if (xL >= 0) scan4(starts[rb + xL], starts[rb + xL + 1]);
                            int xR = cx + r;
                            if (xR <= 31) scan4(starts[rb + xR], starts[rb + xR + 1]);
                        }
                    }
                }
            }
            merge_all();
        }
    }

    // ---- fused gather: float4 channels, 4 passes x 4 queries ----
    uint ki[16];
#pragma unroll
    for (int j = 0; j < 16; ++j) ki[j] = k[j] & 0xFFFFu;

    int ch = lane & 15;          // float4 channel group (4 channels)
    int qg = lane >> 4;          // query within pass
#pragma unroll
    for (int p = 0; p < 4; ++p) {
        int qs = p * 4 + qg;     // query slot 0..15; lane qs holds it (slice 0)
        uint qorig = __shfl(qidx, qs, 64);
        float4 acc = make_float4(0.f, 0.f, 0.f, 0.f);
#pragma unroll
        for (int j = 0; j < 16; ++j) {
            uint nj = __shfl(ki[j], qs, 64);
            float4 v = reinterpret_cast<const float4*>(feat)[nj * 16u + (uint)ch];
            acc.x += v.x; acc.y += v.y; acc.z += v.z; acc.w += v.w;
        }
        reinterpret_cast<float4*>(out)[qorig * 16u + (uint)ch] = acc;
    }
}

extern "C" void kernel_launch(void* const* d_in, const int* in_sizes, int n_in,
                              void* d_out, int out_size, void* d_ws, size_t ws_size,
                              hipStream_t stream) {
    const int*   coords = (const int*)d_in[0];
    const float* feat   = (const float*)d_in[1];
    float*       out    = (float*)d_out;

    uint* W = (uint*)d_ws;
    uint*  chunktot = W;                      // 128 (written by chunk_reduce)
    uint*  counts   = W + 128;                // 32768, memset-zeroed
    uint*  starts   = W + 32896;              // 32769
    uint*  cursors  = W + 65668;              // 32768 (16B aligned)
    uint2* sorted   = (uint2*)(W + 98436);    // 65536 * 8 B (16B aligned)

    hipMemsetAsync(counts, 0, NCELL * sizeof(uint), stream);
    cell_count<<<NPTS / 256, 256, 0, stream>>>(coords, counts);
    chunk_reduce<<<NCELL / 256, 256, 0, stream>>>(counts, chunktot);
    scan_chunk<<<NCELL / 256, 256, 0, stream>>>(counts, chunktot, starts, cursors);
    cell_scatter<<<NPTS / 256, 256, 0, stream>>>(coords, cursors, sorted);
    knn_search<<<1024, 256, 0, stream>>>(starts, sorted, feat, out);
}